// Round 1
// baseline (3331.960 us; speedup 1.0000x reference)
//
#include <hip/hip_runtime.h>
#include <math.h>

#define B_  2048
#define T_  512
#define D_  8
#define H_  80
#define G4  320
#define NB  8
#define TCHUNK 64
#define NTHREADS 640

__device__ __forceinline__ float sigm(float x) {
  return __builtin_amdgcn_rcpf(1.0f + __expf(-x));
}
// overflow-safe tanh: e = exp(-2|x|) in (0,1], no inf/NaN anywhere
__device__ __forceinline__ float tanh_(float x) {
  float ax = fabsf(x);
  float e  = __expf(-2.0f * ax);
  float t  = (1.0f - e) * __builtin_amdgcn_rcpf(1.0f + e);
  return copysignf(t, x);
}

// Persistent fused 2-layer LSTM.
// block = 640 threads (10 waves) = 8 sequences for all T.
// matvec role: jp=tid>>2 owns rows {jp, jp+160}; kq=tid&3 owns k in [20kq,20kq+20)
// update role: ub=tid/80, um=tid%80  (640 = 8*80 exactly)
__global__ __launch_bounds__(NTHREADS, 3)
void lstm2_fused(const float* __restrict__ X,
                 const float* __restrict__ Wih0, const float* __restrict__ Whh0,
                 const float* __restrict__ bih0, const float* __restrict__ bhh0,
                 const float* __restrict__ Wih1, const float* __restrict__ Whh1,
                 const float* __restrict__ bih1, const float* __restrict__ bhh1,
                 const int* __restrict__ slen,
                 float* __restrict__ out)
{
  const int tid   = threadIdx.x;
  const int bbase = blockIdx.x * NB;

  const int jp = tid >> 2;
  const int kq = tid & 3;
  const int j0 = jp, j1 = jp + 160;
  const int kb = kq * 20;

  const int ub = tid / 80;
  const int um = tid - ub * 80;

  __shared__ float xch[NB][TCHUNK][D_];   // 16 KB staged input chunk
  __shared__ float h0s[NB][H_];
  __shared__ float h1s[NB][H_];
  __shared__ float gs[NB][G4];            // gate preacts
  __shared__ int   mls;

  for (int i = tid; i < NB * H_; i += NTHREADS) {
    (&h0s[0][0])[i] = 0.0f; (&h1s[0][0])[i] = 0.0f;
  }
  if (tid == 0) mls = 0;
  __syncthreads();
  if (tid < NB) atomicMax(&mls, slen[bbase + tid]);
  const int lenb = slen[bbase + ub];

  // ---- weights into VGPRs (persistent) ----
  float wh0[2][20], wi1[2][20], wh1[2][20], wi0[2][2], bias0[2], bias1[2];
  #pragma unroll
  for (int r = 0; r < 2; ++r) {
    const int j = r ? j1 : j0;
    const float4* p;
    p = (const float4*)(Whh0 + j * H_ + kb);
    #pragma unroll
    for (int q = 0; q < 5; ++q) { float4 v = p[q];
      wh0[r][4*q+0]=v.x; wh0[r][4*q+1]=v.y; wh0[r][4*q+2]=v.z; wh0[r][4*q+3]=v.w; }
    p = (const float4*)(Wih1 + j * H_ + kb);
    #pragma unroll
    for (int q = 0; q < 5; ++q) { float4 v = p[q];
      wi1[r][4*q+0]=v.x; wi1[r][4*q+1]=v.y; wi1[r][4*q+2]=v.z; wi1[r][4*q+3]=v.w; }
    p = (const float4*)(Whh1 + j * H_ + kb);
    #pragma unroll
    for (int q = 0; q < 5; ++q) { float4 v = p[q];
      wh1[r][4*q+0]=v.x; wh1[r][4*q+1]=v.y; wh1[r][4*q+2]=v.z; wh1[r][4*q+3]=v.w; }
    wi0[r][0] = Wih0[j * D_ + kq * 2 + 0];
    wi0[r][1] = Wih0[j * D_ + kq * 2 + 1];
    // bias/4 per kq lane: 4-lane shfl sum reconstructs exact bias (x*0.25 exact)
    bias0[r] = 0.25f * (bih0[j] + bhh0[j]);
    bias1[r] = 0.25f * (bih1[j] + bhh1[j]);
  }
  __syncthreads();
  const int mlen = mls;
  float c0 = 0.0f, c1 = 0.0f;

  #pragma unroll 1
  for (int t = 0; t < mlen; ++t) {
    const int tc = t & (TCHUNK - 1);
    if (tc == 0) {
      __syncthreads();  // prior readers of xch are done (loop-end barrier), writers fence
      const size_t gbase = (size_t)bbase * (T_ * D_) + (size_t)t * D_;
      for (int idx = tid; idx < NB * TCHUNK * D_; idx += NTHREADS) {
        const int b = idx >> 9;          // 512 floats per sequence chunk
        const int r = idx & 511;
        (&xch[0][0][0])[idx] = X[gbase + (size_t)b * (T_ * D_) + r];
      }
      __syncthreads();
    }

    // ---------- layer 0 matvec: g = b + Wih0*x_t + Whh0*h0 ----------
    #pragma unroll 4
    for (int b = 0; b < NB; ++b) {
      float a0 = bias0[0], a1 = bias0[1];
      const float2 xv = *(const float2*)&xch[b][tc][kq * 2];
      a0 += wi0[0][0]*xv.x; a0 += wi0[0][1]*xv.y;
      a1 += wi0[1][0]*xv.x; a1 += wi0[1][1]*xv.y;
      const float4* hp = (const float4*)&h0s[b][kb];
      #pragma unroll
      for (int q = 0; q < 5; ++q) {
        const float4 hv = hp[q];
        a0 += wh0[0][4*q+0]*hv.x; a0 += wh0[0][4*q+1]*hv.y;
        a0 += wh0[0][4*q+2]*hv.z; a0 += wh0[0][4*q+3]*hv.w;
        a1 += wh0[1][4*q+0]*hv.x; a1 += wh0[1][4*q+1]*hv.y;
        a1 += wh0[1][4*q+2]*hv.z; a1 += wh0[1][4*q+3]*hv.w;
      }
      a0 += __shfl_xor(a0, 1); a0 += __shfl_xor(a0, 2);
      a1 += __shfl_xor(a1, 1); a1 += __shfl_xor(a1, 2);
      if (kq == 0) { gs[b][j0] = a0; gs[b][j1] = a1; }
    }
    __syncthreads();

    // ---------- layer 0 gate update ----------
    {
      const float gi = gs[ub][um],      gf = gs[ub][80 + um];
      const float gg = gs[ub][160 + um], go = gs[ub][240 + um];
      c0 = sigm(gf) * c0 + sigm(gi) * tanh_(gg);
      h0s[ub][um] = sigm(go) * tanh_(c0);
    }
    __syncthreads();

    // ---------- layer 1 matvec: g = b + Wih1*h0_new + Whh1*h1 ----------
    #pragma unroll 4
    for (int b = 0; b < NB; ++b) {
      float a0 = bias1[0], a1 = bias1[1];
      const float4* up = (const float4*)&h0s[b][kb];
      const float4* vp = (const float4*)&h1s[b][kb];
      #pragma unroll
      for (int q = 0; q < 5; ++q) {
        const float4 u = up[q];
        const float4 v = vp[q];
        a0 += wi1[0][4*q+0]*u.x; a0 += wi1[0][4*q+1]*u.y;
        a0 += wi1[0][4*q+2]*u.z; a0 += wi1[0][4*q+3]*u.w;
        a0 += wh1[0][4*q+0]*v.x; a0 += wh1[0][4*q+1]*v.y;
        a0 += wh1[0][4*q+2]*v.z; a0 += wh1[0][4*q+3]*v.w;
        a1 += wi1[1][4*q+0]*u.x; a1 += wi1[1][4*q+1]*u.y;
        a1 += wi1[1][4*q+2]*u.z; a1 += wi1[1][4*q+3]*u.w;
        a1 += wh1[1][4*q+0]*v.x; a1 += wh1[1][4*q+1]*v.y;
        a1 += wh1[1][4*q+2]*v.z; a1 += wh1[1][4*q+3]*v.w;
      }
      a0 += __shfl_xor(a0, 1); a0 += __shfl_xor(a0, 2);
      a1 += __shfl_xor(a1, 1); a1 += __shfl_xor(a1, 2);
      if (kq == 0) { gs[b][j0] = a0; gs[b][j1] = a1; }
    }
    __syncthreads();

    // ---------- layer 1 gate update + output gather ----------
    {
      const float gi = gs[ub][um],      gf = gs[ub][80 + um];
      const float gg = gs[ub][160 + um], go = gs[ub][240 + um];
      c1 = sigm(gf) * c1 + sigm(gi) * tanh_(gg);
      const float h = sigm(go) * tanh_(c1);
      h1s[ub][um] = h;
      if (t == lenb - 1) out[(size_t)(bbase + ub) * H_ + um] = h;
    }
    __syncthreads();
  }
}

extern "C" void kernel_launch(void* const* d_in, const int* in_sizes, int n_in,
                              void* d_out, int out_size, void* d_ws, size_t ws_size,
                              hipStream_t stream) {
  const float* X    = (const float*)d_in[0];
  const float* Wih0 = (const float*)d_in[1];
  const float* Whh0 = (const float*)d_in[2];
  const float* bih0 = (const float*)d_in[3];
  const float* bhh0 = (const float*)d_in[4];
  const float* Wih1 = (const float*)d_in[5];
  const float* Whh1 = (const float*)d_in[6];
  const float* bih1 = (const float*)d_in[7];
  const float* bhh1 = (const float*)d_in[8];
  const int*   slen = (const int*)d_in[9];

  lstm2_fused<<<B_ / NB, NTHREADS, 0, stream>>>(
      X, Wih0, Whh0, bih0, bhh0, Wih1, Whh1, bih1, bhh1, slen, (float*)d_out);
}

// Round 3
// 1802.084 us; speedup vs baseline: 1.8489x; 1.8489x over previous
//
#include <hip/hip_runtime.h>
#include <math.h>

#define B_  2048
#define T_  512
#define D_  8
#define H_  80
#define G4  320
#define NB  4
#define NQ  (B_ / NB)      // 512 work quads
#define TCHUNK 64
#define NTH 640            // 10 waves (<= 1024 max block size!)
#define NWORK 256          // persistent workers, 1 per CU

typedef float v2f __attribute__((ext_vector_type(2)));
typedef float v4f __attribute__((ext_vector_type(4)));

__device__ __forceinline__ float sigm(float x) {
  return __builtin_amdgcn_rcpf(1.0f + __expf(-x));
}
__device__ __forceinline__ float tanh_(float x) {   // overflow-safe
  float ax = fabsf(x);
  float e  = __expf(-2.0f * ax);
  float t  = (1.0f - e) * __builtin_amdgcn_rcpf(1.0f + e);
  return copysignf(t, x);
}

// ---- counting sort by length, DESCENDING; also zeroes the work counter ----
__global__ __launch_bounds__(512)
void sort_by_len(const int* __restrict__ slen, int* __restrict__ perm,
                 int* __restrict__ ctr) {
  __shared__ int cnt[513];
  const int tid = threadIdx.x;
  if (tid == 0) ctr[0] = 0;
  for (int i = tid; i < 513; i += 512) cnt[i] = 0;
  __syncthreads();
  for (int b = tid; b < B_; b += 512) atomicAdd(&cnt[T_ - slen[b]], 1);
  __syncthreads();
  if (tid == 0) { int s = 0;
    for (int k = 0; k < 513; ++k) { int c = cnt[k]; cnt[k] = s; s += c; } }
  __syncthreads();
  for (int b = tid; b < B_; b += 512) {
    int pos = atomicAdd(&cnt[T_ - slen[b]], 1);
    perm[pos] = b;   // order within equal lengths irrelevant: per-seq results independent
  }
}

__device__ __forceinline__ void load20(v2f* d, const float* s) {
  #pragma unroll
  for (int q = 0; q < 5; ++q) {
    v4f v = *(const v4f*)(s + 4 * q);
    d[2*q]   = (v2f){v.x, v.y};
    d[2*q+1] = (v2f){v.z, v.w};
  }
}

// ---- persistent fused 2-layer LSTM, LPT queue over sorted quads ----
// matvec role: jp=tid>>2 owns rows {jp, jp+160}; kq=tid&3 owns k in [20kq,20kq+20)
// update role: tid<320 -> ub=tid/80 (seq in quad), um=tid%80 (hidden unit)
__global__ __launch_bounds__(NTH) __attribute__((amdgpu_waves_per_eu(3, 3)))
void lstm2_fused(const float* __restrict__ X,
                 const float* __restrict__ Wih0, const float* __restrict__ Whh0,
                 const float* __restrict__ bih0, const float* __restrict__ bhh0,
                 const float* __restrict__ Wih1, const float* __restrict__ Whh1,
                 const float* __restrict__ bih1, const float* __restrict__ bhh1,
                 const int* __restrict__ slen, const int* __restrict__ perm,
                 int* __restrict__ ctr, float* __restrict__ out)
{
  const int tid = threadIdx.x;
  const int jp = tid >> 2;
  const int kq = tid & 3;
  const int kb = kq * 20;
  const int ub = (tid < G4) ? tid / 80 : 0;
  const int um = tid - ub * 80;

  __shared__ float xch[NB][TCHUNK][D_];   // 8 KB
  __shared__ float h0s[NB][H_];
  __shared__ float h1s[NB][H_];
  __shared__ float gs[NB][G4];
  __shared__ int   pbs[NB];
  __shared__ int   mls, qsh;

  // ---- persistent weights: 60 v2f = 120 VGPRs ----
  v2f wh0v[2][10], wi1v[2][10], wh1v[2][10], wi0v[2];
  float bias0[2], bias1[2];
  #pragma unroll
  for (int r = 0; r < 2; ++r) {
    const int j = jp + 160 * r;
    load20(wh0v[r], Whh0 + j * H_ + kb);
    load20(wi1v[r], Wih1 + j * H_ + kb);
    load20(wh1v[r], Whh1 + j * H_ + kb);
    wi0v[r] = *(const v2f*)(Wih0 + j * D_ + kq * 2);
    bias0[r] = bih0[j] + bhh0[j];
    bias1[r] = bih1[j] + bhh1[j];
  }

  while (true) {
    __syncthreads();                       // previous quad fully done with LDS
    if (tid == 0) qsh = atomicAdd(ctr, 1);
    __syncthreads();
    const int q = qsh;
    if (q >= NQ) break;

    if (tid < NB * H_) { ((float*)h0s)[tid] = 0.0f; ((float*)h1s)[tid] = 0.0f; }
    if (tid == 0) mls = 0;
    __syncthreads();
    if (tid < NB) {
      int pb = perm[q * NB + tid];
      pbs[tid] = pb;
      atomicMax(&mls, slen[pb]);
    }
    __syncthreads();
    const int mlen = mls;
    const int lenb = (tid < NB * H_) ? slen[pbs[ub]] : 0;
    float c0 = 0.0f, c1 = 0.0f;

    #pragma unroll 1
    for (int t = 0; t < mlen; ++t) {
      const int tc = t & (TCHUNK - 1);
      if (tc == 0) {
        __syncthreads();                   // prior readers of xch done
        if (tid < 512) {                   // 512 float4 = NB*TCHUNK*D_ floats
          const int b = tid >> 7, r4 = tid & 127;
          v4f v = *(const v4f*)(X + (size_t)pbs[b] * (T_ * D_)
                                  + (size_t)t * D_ + r4 * 4);
          *((v4f*)xch + tid) = v;
        }
        __syncthreads();
      }

      // ---------- layer 0 matvec ----------
      #pragma unroll 2
      for (int b = 0; b < NB; ++b) {
        const v4f* hp = (const v4f*)&h0s[b][kb];
        v2f ac0 = {0.f, 0.f}, ac1 = {0.f, 0.f};
        #pragma unroll
        for (int q5 = 0; q5 < 5; ++q5) {
          v4f h4 = hp[q5];
          v2f hA = {h4.x, h4.y}, hB = {h4.z, h4.w};
          ac0 += wh0v[0][2*q5] * hA; ac0 += wh0v[0][2*q5+1] * hB;
          ac1 += wh0v[1][2*q5] * hA; ac1 += wh0v[1][2*q5+1] * hB;
        }
        v2f xv = *(const v2f*)&xch[b][tc][kq * 2];
        ac0 += wi0v[0] * xv;
        ac1 += wi0v[1] * xv;
        float a0 = ac0.x + ac0.y;
        float a1 = ac1.x + ac1.y;
        a0 += __shfl_xor(a0, 1); a0 += __shfl_xor(a0, 2);
        a1 += __shfl_xor(a1, 1); a1 += __shfl_xor(a1, 2);
        if (kq == 0) { gs[b][jp] = a0 + bias0[0]; gs[b][jp + 160] = a1 + bias0[1]; }
      }
      __syncthreads();

      // ---------- layer 0 update ----------
      if (tid < NB * H_) {
        const float gi = gs[ub][um],       gf = gs[ub][80 + um];
        const float gg = gs[ub][160 + um], go = gs[ub][240 + um];
        c0 = sigm(gf) * c0 + sigm(gi) * tanh_(gg);
        h0s[ub][um] = sigm(go) * tanh_(c0);
      }
      __syncthreads();

      // ---------- layer 1 matvec ----------
      #pragma unroll 2
      for (int b = 0; b < NB; ++b) {
        const v4f* up = (const v4f*)&h0s[b][kb];
        const v4f* vp = (const v4f*)&h1s[b][kb];
        v2f ac0 = {0.f, 0.f}, ac1 = {0.f, 0.f};
        #pragma unroll
        for (int q5 = 0; q5 < 5; ++q5) {
          v4f u4 = up[q5], v4 = vp[q5];
          v2f uA = {u4.x, u4.y}, uB = {u4.z, u4.w};
          v2f vA = {v4.x, v4.y}, vB = {v4.z, v4.w};
          ac0 += wi1v[0][2*q5] * uA; ac0 += wi1v[0][2*q5+1] * uB;
          ac0 += wh1v[0][2*q5] * vA; ac0 += wh1v[0][2*q5+1] * vB;
          ac1 += wi1v[1][2*q5] * uA; ac1 += wi1v[1][2*q5+1] * uB;
          ac1 += wh1v[1][2*q5] * vA; ac1 += wh1v[1][2*q5+1] * vB;
        }
        float a0 = ac0.x + ac0.y;
        float a1 = ac1.x + ac1.y;
        a0 += __shfl_xor(a0, 1); a0 += __shfl_xor(a0, 2);
        a1 += __shfl_xor(a1, 1); a1 += __shfl_xor(a1, 2);
        if (kq == 0) { gs[b][jp] = a0 + bias1[0]; gs[b][jp + 160] = a1 + bias1[1]; }
      }
      __syncthreads();

      // ---------- layer 1 update + output ----------
      if (tid < NB * H_) {
        const float gi = gs[ub][um],       gf = gs[ub][80 + um];
        const float gg = gs[ub][160 + um], go = gs[ub][240 + um];
        c1 = sigm(gf) * c1 + sigm(gi) * tanh_(gg);
        const float h = sigm(go) * tanh_(c1);
        h1s[ub][um] = h;
        if (t == lenb - 1) out[(size_t)pbs[ub] * H_ + um] = h;
      }
      __syncthreads();
    }
  }
}

extern "C" void kernel_launch(void* const* d_in, const int* in_sizes, int n_in,
                              void* d_out, int out_size, void* d_ws, size_t ws_size,
                              hipStream_t stream) {
  const float* X    = (const float*)d_in[0];
  const float* Wih0 = (const float*)d_in[1];
  const float* Whh0 = (const float*)d_in[2];
  const float* bih0 = (const float*)d_in[3];
  const float* bhh0 = (const float*)d_in[4];
  const float* Wih1 = (const float*)d_in[5];
  const float* Whh1 = (const float*)d_in[6];
  const float* bih1 = (const float*)d_in[7];
  const float* bhh1 = (const float*)d_in[8];
  const int*   slen = (const int*)d_in[9];

  int* perm = (int*)d_ws;        // 2048 ints
  int* ctr  = perm + B_;         // 1 int

  sort_by_len<<<1, 512, 0, stream>>>(slen, perm, ctr);
  lstm2_fused<<<NWORK, NTH, 0, stream>>>(
      X, Wih0, Whh0, bih0, bhh0, Wih1, Whh1, bih1, bhh1, slen, perm, ctr,
      (float*)d_out);
}

// Round 4
// 1034.373 us; speedup vs baseline: 3.2212x; 1.7422x over previous
//
#include <hip/hip_runtime.h>
#include <math.h>

#define B_   2048
#define T_   512
#define D_   8
#define H_   80
#define NB   16
#define NBLK (B_ / NB)     // 128 blocks
#define NTH  320           // 5 waves
#define KS0  3             // A0: K=96  = [x_hi(8) | x_lo(8) | h0(80)]
#define KS1  5             // A1: K=160 = [h0(80) | h1(80)]
#define A0S  256           // A0 row stride bytes (128 bf16) - multiple of 128B for swizzle
#define A1S  384           // A1 row stride bytes (192 bf16)
#define A0BUF (16 * A0S)
#define A1BUF (16 * A1S)

typedef float f32x4  __attribute__((ext_vector_type(4)));
typedef short bf16x8 __attribute__((ext_vector_type(8)));

__device__ __forceinline__ float sigm(float x) {
  return __builtin_amdgcn_rcpf(1.0f + __expf(-x));
}
__device__ __forceinline__ float tanh_(float x) {   // overflow-safe
  float ax = fabsf(x);
  float e  = __expf(-2.0f * ax);
  float t  = (1.0f - e) * __builtin_amdgcn_rcpf(1.0f + e);
  return copysignf(t, x);
}
__device__ __forceinline__ unsigned short f2bf(float f) {  // RNE f32->bf16
  unsigned u = __builtin_bit_cast(unsigned, f);
  return (unsigned short)((u + 0x7FFFu + ((u >> 16) & 1u)) >> 16);
}
__device__ __forceinline__ float bf2f(unsigned short b) {
  unsigned u = ((unsigned)b) << 16;
  return __builtin_bit_cast(float, u);
}
// XOR swizzle within a row (stride multiple of 128B): kills bank conflicts on
// 16-lane same-column b128 reads (2 lanes/bank = free per m136).
__device__ __forceinline__ int swz(int row, int byte_in_row) {
  return byte_in_row ^ ((row & 7) << 4);
}

// ---- counting sort by length, DESCENDING ----
__global__ __launch_bounds__(512)
void sort_by_len(const int* __restrict__ slen, int* __restrict__ perm) {
  __shared__ int cnt[513];
  const int tid = threadIdx.x;
  for (int i = tid; i < 513; i += 512) cnt[i] = 0;
  __syncthreads();
  for (int b = tid; b < B_; b += 512) atomicAdd(&cnt[T_ - slen[b]], 1);
  __syncthreads();
  if (tid == 0) { int s = 0;
    for (int k = 0; k < 513; ++k) { int c = cnt[k]; cnt[k] = s; s += c; } }
  __syncthreads();
  for (int b = tid; b < B_; b += 512) {
    int pos = atomicAdd(&cnt[T_ - slen[b]], 1);
    perm[pos] = b;   // equal-length order arbitrary: per-seq results independent
  }
}

// ---- fused 2-layer LSTM, one block = one group of 16 sorted seqs ----
// wave w owns units [16w,16w+16); its 4 gate-tiles (i,f,g,o) for those units.
// C layout (m89): col = lane&15 (unit), row = (lane>>4)*4 + reg (seq).
__global__ __launch_bounds__(NTH, 2)
void lstm2_mfma(const float* __restrict__ X,
                const float* __restrict__ Wih0, const float* __restrict__ Whh0,
                const float* __restrict__ bih0, const float* __restrict__ bhh0,
                const float* __restrict__ Wih1, const float* __restrict__ Whh1,
                const float* __restrict__ bih1, const float* __restrict__ bhh1,
                const int* __restrict__ slen, const int* __restrict__ perm,
                float* __restrict__ out)
{
  __shared__ char a0lds[2 * A0BUF];   // bf16 [16][128], swizzled, double-buffered
  __shared__ char a1lds[2 * A1BUF];   // bf16 [16][192], swizzled, double-buffered
  __shared__ int  pbs[NB];
  __shared__ int  lns[NB];

  const int tid = threadIdx.x;
  const int w   = tid >> 6;         // wave 0..4
  const int l   = tid & 63;
  const int lr  = l & 15;           // A-frag row / C col offset
  const int q   = l >> 4;           // k-octet / C row-block
  const int n0  = 16 * w + lr;      // this lane's hidden unit (0..79)

  if (tid < NB) {
    int pb = perm[blockIdx.x * NB + tid];
    pbs[tid] = pb;
    lns[tid] = slen[pb];
  }

  // ---- weight B-fragments into VGPRs (once). B[k][n] = W[n][k]. ----
  // frag elem j <-> k = 32*ks + 8*q + j (contiguous-8 layout), n = 80*g + n0.
  bf16x8 w0[KS0][4], w1[KS1][4];
  float  bias0[4], bias1[4];
  #pragma unroll
  for (int g = 0; g < 4; ++g) {
    const int n = 80 * g + n0;
    bias0[g] = bih0[n] + bhh0[n];
    bias1[g] = bih1[n] + bhh1[n];
    #pragma unroll
    for (int ks = 0; ks < KS0; ++ks) {
      bf16x8 v;
      #pragma unroll
      for (int j = 0; j < 8; ++j) {
        int k = 32 * ks + 8 * q + j;
        float f = (k < 8)  ? Wih0[n * D_ + k]          // x_hi rows
                : (k < 16) ? Wih0[n * D_ + (k - 8)]    // x_lo rows (same W)
                           : Whh0[n * H_ + (k - 16)];  // h0 rows
        v[j] = (short)f2bf(f);
      }
      w0[ks][g] = v;
    }
    #pragma unroll
    for (int ks = 0; ks < KS1; ++ks) {
      bf16x8 v;
      #pragma unroll
      for (int j = 0; j < 8; ++j) {
        int k = 32 * ks + 8 * q + j;
        float f = (k < 80) ? Wih1[n * H_ + k] : Whh1[n * H_ + (k - 80)];
        v[j] = (short)f2bf(f);
      }
      w1[ks][g] = v;
    }
  }

  // ---- zero both LDS buffers (h=0 initial state, pads) ----
  for (int i = tid; i < (2 * A0BUF) / 4; i += NTH) ((int*)a0lds)[i] = 0;
  for (int i = tid; i < (2 * A1BUF) / 4; i += NTH) ((int*)a1lds)[i] = 0;
  __syncthreads();

  const int mlen = lns[0];          // descending sort -> row 0 has the max len

  int seq4[4], len4[4];
  #pragma unroll
  for (int r = 0; r < 4; ++r) {
    int row = 4 * q + r;
    seq4[r] = pbs[row];
    len4[r] = lns[row];
  }

  // ---- x prologue: x_0 -> A0[0] (hi+lo bf16), prefetch x_1 into regs ----
  const int xrow = tid >> 4, xcc = tid & 15, xd = xcc & 7;
  const float* xptr = nullptr;
  float xr = 0.f;
  if (tid < 256) {
    xptr = X + (size_t)pbs[xrow] * (T_ * D_) + xd;
    float v0 = xptr[0];
    unsigned short hb;
    if (xcc < 8) hb = f2bf(v0);
    else { float hi = bf2f(f2bf(v0)); hb = f2bf(v0 - hi); }
    *(unsigned short*)(a0lds + xrow * A0S + swz(xrow, xcc * 2)) = hb;
    int t1 = (mlen > 1) ? 1 : 0;
    xr = xptr[D_ * t1];
  }
  __syncthreads();

  float c0[4] = {0.f, 0.f, 0.f, 0.f};
  float c1[4] = {0.f, 0.f, 0.f, 0.f};
  int p = 0;

  #pragma unroll 1
  for (int t = 0; t < mlen; ++t) {
    const char* A0p = a0lds + p * A0BUF;
    char*       A0n = a0lds + (p ^ 1) * A0BUF;
    const char* A1p = a1lds + p * A1BUF;
    char*       A1n = a1lds + (p ^ 1) * A1BUF;

    // ---------- layer 0 MFMA: gates0 = A0[p] * W0 ----------
    f32x4 ac0 = {}, ac1 = {}, ac2 = {}, ac3 = {};
    #pragma unroll
    for (int ks = 0; ks < KS0; ++ks) {
      bf16x8 a = *(const bf16x8*)(A0p + lr * A0S + swz(lr, 64 * ks + 16 * q));
      ac0 = __builtin_amdgcn_mfma_f32_16x16x32_bf16(a, w0[ks][0], ac0, 0, 0, 0);
      ac1 = __builtin_amdgcn_mfma_f32_16x16x32_bf16(a, w0[ks][1], ac1, 0, 0, 0);
      ac2 = __builtin_amdgcn_mfma_f32_16x16x32_bf16(a, w0[ks][2], ac2, 0, 0, 0);
      ac3 = __builtin_amdgcn_mfma_f32_16x16x32_bf16(a, w0[ks][3], ac3, 0, 0, 0);
    }

    // ---------- stage x_{t+1} (hi+lo) into A0n; prefetch x_{t+2} ----------
    if (tid < 256) {
      unsigned short hb;
      if (xcc < 8) hb = f2bf(xr);
      else { float hi = bf2f(f2bf(xr)); hb = f2bf(xr - hi); }
      *(unsigned short*)(A0n + xrow * A0S + swz(xrow, xcc * 2)) = hb;
      int t2 = t + 2; if (t2 > mlen - 1) t2 = mlen - 1;
      xr = xptr[D_ * t2];
    }

    // ---------- layer 0 update (in-register i,f,g,o) ----------
    #pragma unroll
    for (int r = 0; r < 4; ++r) {
      const int row = 4 * q + r;
      float gi = ac0[r] + bias0[0];
      float gf = ac1[r] + bias0[1];
      float gg = ac2[r] + bias0[2];
      float go = ac3[r] + bias0[3];
      c0[r] = sigm(gf) * c0[r] + sigm(gi) * tanh_(gg);
      float h = sigm(go) * tanh_(c0[r]);
      unsigned short hb = f2bf(h);
      *(unsigned short*)(A1p + row * A1S + swz(row, n0 * 2)) = hb;       // L1 input (now)
      *(unsigned short*)(A0n + row * A0S + swz(row, 32 + n0 * 2)) = hb;  // L0 input (t+1)
    }
    __syncthreads();   // B1: h0 writes visible before L1 reads

    // ---------- layer 1 MFMA: gates1 = A1[p] * W1 ----------
    f32x4 bc0 = {}, bc1 = {}, bc2 = {}, bc3 = {};
    #pragma unroll
    for (int ks = 0; ks < KS1; ++ks) {
      bf16x8 a = *(const bf16x8*)(A1p + lr * A1S + swz(lr, 64 * ks + 16 * q));
      bc0 = __builtin_amdgcn_mfma_f32_16x16x32_bf16(a, w1[ks][0], bc0, 0, 0, 0);
      bc1 = __builtin_amdgcn_mfma_f32_16x16x32_bf16(a, w1[ks][1], bc1, 0, 0, 0);
      bc2 = __builtin_amdgcn_mfma_f32_16x16x32_bf16(a, w1[ks][2], bc2, 0, 0, 0);
      bc3 = __builtin_amdgcn_mfma_f32_16x16x32_bf16(a, w1[ks][3], bc3, 0, 0, 0);
    }

    // ---------- layer 1 update + output ----------
    #pragma unroll
    for (int r = 0; r < 4; ++r) {
      const int row = 4 * q + r;
      float gi = bc0[r] + bias1[0];
      float gf = bc1[r] + bias1[1];
      float gg = bc2[r] + bias1[2];
      float go = bc3[r] + bias1[3];
      c1[r] = sigm(gf) * c1[r] + sigm(gi) * tanh_(gg);
      float h = sigm(go) * tanh_(c1[r]);
      *(unsigned short*)(A1n + row * A1S + swz(row, 160 + n0 * 2)) = f2bf(h); // h1 (t+1)
      if (t == len4[r] - 1) out[(size_t)seq4[r] * H_ + n0] = h;
    }
    __syncthreads();   // B2: h1/x writes visible before next step
    p ^= 1;
  }
}

extern "C" void kernel_launch(void* const* d_in, const int* in_sizes, int n_in,
                              void* d_out, int out_size, void* d_ws, size_t ws_size,
                              hipStream_t stream) {
  const float* X    = (const float*)d_in[0];
  const float* Wih0 = (const float*)d_in[1];
  const float* Whh0 = (const float*)d_in[2];
  const float* bih0 = (const float*)d_in[3];
  const float* bhh0 = (const float*)d_in[4];
  const float* Wih1 = (const float*)d_in[5];
  const float* Whh1 = (const float*)d_in[6];
  const float* bih1 = (const float*)d_in[7];
  const float* bhh1 = (const float*)d_in[8];
  const int*   slen = (const int*)d_in[9];
  int* perm = (int*)d_ws;   // 2048 ints

  sort_by_len<<<1, 512, 0, stream>>>(slen, perm);
  lstm2_mfma<<<NBLK, NTH, 0, stream>>>(
      X, Wih0, Whh0, bih0, bhh0, Wih1, Whh1, bih1, bhh1, slen, perm,
      (float*)d_out);
}

// Round 5
// 996.321 us; speedup vs baseline: 3.3443x; 1.0382x over previous
//
#include <hip/hip_runtime.h>
#include <math.h>

#define B_   2048
#define T_   512
#define D_   8
#define H_   80
#define NB   16
#define NBLK (B_ / NB)     // 128 blocks
#define NTH  320           // 5 waves
#define KS0  3             // A0: K=96  = [x_hi(8) | x_lo(8) | h0(80)]
#define KS1  5             // A1: K=160 = [h0(80) | h1(80)]
#define A0S  256           // A0 row stride bytes (128 bf16)
#define A1S  384           // A1 row stride bytes (192 bf16)
#define A0BUF (16 * A0S)   // 4 KB
#define A1BUF (16 * A1S)   // 6 KB

typedef float f32x4  __attribute__((ext_vector_type(4)));
typedef short bf16x8 __attribute__((ext_vector_type(8)));
typedef unsigned short u16x4 __attribute__((ext_vector_type(4)));

__device__ __forceinline__ float sigm(float x) {
  return __builtin_amdgcn_rcpf(1.0f + __expf(-x));
}
__device__ __forceinline__ unsigned short f2bf(float f) {  // RNE f32->bf16
  unsigned u = __builtin_bit_cast(unsigned, f);
  return (unsigned short)((u + 0x7FFFu + ((u >> 16) & 1u)) >> 16);
}
__device__ __forceinline__ float bf2f(unsigned short b) {
  unsigned u = ((unsigned)b) << 16;
  return __builtin_bit_cast(float, u);
}
__device__ __forceinline__ int swz(int row, int byte_in_row) {
  return byte_in_row ^ ((row & 7) << 4);
}
// full LSTM cell: gates -> h, updates c. tanh(x) = 2*sigm(2x)-1 (overflow-safe:
// exp->inf => rcp->0 => sigm->0 => tanh->-1).
__device__ __forceinline__ float cell(float gi, float gf, float gg, float go,
                                      float& c) {
  float si = sigm(gi), sf = sigm(gf);
  float tg = __builtin_fmaf(2.0f, sigm(2.0f * gg), -1.0f);
  c = sf * c + si * tg;
  float th = __builtin_fmaf(2.0f, sigm(2.0f * c), -1.0f);
  return sigm(go) * th;
}

// ---- counting sort by length, DESCENDING ----
__global__ __launch_bounds__(512)
void sort_by_len(const int* __restrict__ slen, int* __restrict__ perm) {
  __shared__ int cnt[513];
  const int tid = threadIdx.x;
  for (int i = tid; i < 513; i += 512) cnt[i] = 0;
  __syncthreads();
  for (int b = tid; b < B_; b += 512) atomicAdd(&cnt[T_ - slen[b]], 1);
  __syncthreads();
  if (tid == 0) { int s = 0;
    for (int k = 0; k < 513; ++k) { int c = cnt[k]; cnt[k] = s; s += c; } }
  __syncthreads();
  for (int b = tid; b < B_; b += 512) {
    int pos = atomicAdd(&cnt[T_ - slen[b]], 1);
    perm[pos] = b;   // equal-length order arbitrary: per-seq results independent
  }
}

// ---- fused 2-layer LSTM, layer-skewed software pipeline ----
// Iteration i computes L1(t=i) || L0(t=i+1); ONE barrier per iteration.
// Buffer parity: L0(t) reads A0[t&1]; L1(t) reads A1[t&1].
// C layout (m89): col = lane&15 (unit), row = (lane>>4)*4 + reg (seq).
__global__ __launch_bounds__(NTH, 1) __attribute__((amdgpu_waves_per_eu(1, 2)))
void lstm2_mfma(const float* __restrict__ X,
                const float* __restrict__ Wih0, const float* __restrict__ Whh0,
                const float* __restrict__ bih0, const float* __restrict__ bhh0,
                const float* __restrict__ Wih1, const float* __restrict__ Whh1,
                const float* __restrict__ bih1, const float* __restrict__ bhh1,
                const int* __restrict__ slen, const int* __restrict__ perm,
                float* __restrict__ out)
{
  __shared__ char a0lds[2 * A0BUF];
  __shared__ char a1lds[2 * A1BUF];
  __shared__ int  pbs[NB];
  __shared__ int  lns[NB];

  const int tid = threadIdx.x;
  const int w   = tid >> 6;
  const int l   = tid & 63;
  const int lr  = l & 15;           // A-frag row / C col
  const int q   = l >> 4;           // k-octet / C row-block
  const int n0  = 16 * w + lr;      // hidden unit

  if (tid < NB) {
    int pb = perm[blockIdx.x * NB + tid];
    pbs[tid] = pb;
    lns[tid] = slen[pb];
  }

  // ---- weight B-fragments into VGPRs. frag elem j <-> k = 32*ks + 8*q + j ----
  bf16x8 w0[KS0][4], w1[KS1][4];
  float  bias0[4], bias1[4];
  #pragma unroll
  for (int g = 0; g < 4; ++g) {
    const int n = 80 * g + n0;
    bias0[g] = bih0[n] + bhh0[n];
    bias1[g] = bih1[n] + bhh1[n];
    #pragma unroll
    for (int ks = 0; ks < KS0; ++ks) {
      bf16x8 v;
      #pragma unroll
      for (int j = 0; j < 8; ++j) {
        int k = 32 * ks + 8 * q + j;
        float f = (k < 8)  ? Wih0[n * D_ + k]
                : (k < 16) ? Wih0[n * D_ + (k - 8)]
                           : Whh0[n * H_ + (k - 16)];
        v[j] = (short)f2bf(f);
      }
      w0[ks][g] = v;
    }
    #pragma unroll
    for (int ks = 0; ks < KS1; ++ks) {
      bf16x8 v;
      #pragma unroll
      for (int j = 0; j < 8; ++j) {
        int k = 32 * ks + 8 * q + j;
        float f = (k < 80) ? Wih1[n * H_ + k] : Whh1[n * H_ + (k - 80)];
        v[j] = (short)f2bf(f);
      }
      w1[ks][g] = v;
    }
  }

  for (int i = tid; i < (2 * A0BUF) / 4; i += NTH) ((int*)a0lds)[i] = 0;
  for (int i = tid; i < (2 * A1BUF) / 4; i += NTH) ((int*)a1lds)[i] = 0;
  __syncthreads();                      // pbs/lns + zeros visible

  const int mlen = lns[0];              // descending sort: row 0 = group max
  int seq4[4], len4[4];
  #pragma unroll
  for (int r = 0; r < 4; ++r) {
    int row = 4 * q + r;
    seq4[r] = pbs[row];
    len4[r] = lns[row];
  }

  // ---- x machinery: lane (xs,xt,xh) owns x[seq=xs][chunk+xt][4*xh..+4) ----
  const int xs = tid >> 4, xt = (tid & 15) >> 1, xh = tid & 1;
  const float* xbase = nullptr;
  f32x4 xa = {}, xb = {};
  if (tid < 256) {
    xbase = X + (size_t)pbs[xs] * (T_ * D_) + 4 * xh;
    int t0 = xt;          if (t0 > T_ - 1) t0 = T_ - 1;
    int t1 = 8 + xt;      if (t1 > T_ - 1) t1 = T_ - 1;
    xa = *(const f32x4*)(xbase + t0 * D_);
    xb = *(const f32x4*)(xbase + t1 * D_);
  }

  // stage x(0) -> A0[0], x(1) -> A0[1]  (hi cols 0..7, lo cols 8..15)
  #pragma unroll
  for (int tt = 0; tt < 2; ++tt) {
    if (tid < 256 && xt == tt) {
      u16x4 hi, lo;
      #pragma unroll
      for (int j = 0; j < 4; ++j) {
        hi[j] = f2bf(xa[j]);
        lo[j] = f2bf(xa[j] - bf2f(hi[j]));
      }
      char* buf = a0lds + tt * A0BUF;
      *(u16x4*)(buf + xs * A0S + swz(xs, 8 * xh))      = hi;
      *(u16x4*)(buf + xs * A0S + swz(xs, 16 + 8 * xh)) = lo;
    }
  }
  __syncthreads();                      // x(0) visible

  float c0[4] = {0.f, 0.f, 0.f, 0.f};
  float c1[4] = {0.f, 0.f, 0.f, 0.f};

  // ---- prologue: L0(0) ----
  {
    const char* A0p = a0lds;            // A0[0]
    f32x4 a0c0 = {}, a0c1 = {}, a0c2 = {}, a0c3 = {};
    #pragma unroll
    for (int ks = 0; ks < KS0; ++ks) {
      bf16x8 a = *(const bf16x8*)(A0p + lr * A0S + swz(lr, 64 * ks + 16 * q));
      a0c0 = __builtin_amdgcn_mfma_f32_16x16x32_bf16(a, w0[ks][0], a0c0, 0, 0, 0);
      a0c1 = __builtin_amdgcn_mfma_f32_16x16x32_bf16(a, w0[ks][1], a0c1, 0, 0, 0);
      a0c2 = __builtin_amdgcn_mfma_f32_16x16x32_bf16(a, w0[ks][2], a0c2, 0, 0, 0);
      a0c3 = __builtin_amdgcn_mfma_f32_16x16x32_bf16(a, w0[ks][3], a0c3, 0, 0, 0);
    }
    char* A1w = a1lds;                  // A1[0] h0-region
    char* A0w = a0lds + A0BUF;          // A0[1] h0-region
    #pragma unroll
    for (int r = 0; r < 4; ++r) {
      const int row = 4 * q + r;
      float h = cell(a0c0[r] + bias0[0], a0c1[r] + bias0[1],
                     a0c2[r] + bias0[2], a0c3[r] + bias0[3], c0[r]);
      unsigned short hb = f2bf(h);
      *(unsigned short*)(A1w + row * A1S + swz(row, 2 * n0)) = hb;
      *(unsigned short*)(A0w + row * A0S + swz(row, 32 + 2 * n0)) = hb;
    }
  }
  __syncthreads();                      // h0(0), x(1) visible

  // ---- main loop: iteration i = { L1(i) || L0(i+1) }, one barrier ----
  #pragma unroll 2
  for (int i = 0; i < mlen; ++i) {
    const int cur = i & 1, nxt = cur ^ 1;

    // refill: every 8 iters rotate chunk regs, issue next-chunk loads
    if (tid < 256 && ((i + 2) & 7) == 0) {
      xa = xb;
      int tc = i + 10 + xt; if (tc > T_ - 1) tc = T_ - 1;
      xb = *(const f32x4*)(xbase + tc * D_);
    }

    const char* A1p = a1lds + cur * A1BUF;   // L1(i) input
    const char* A0p = a0lds + nxt * A0BUF;   // L0(i+1) input

    f32x4 b0 = {}, b1 = {}, b2 = {}, b3 = {};
    f32x4 a0 = {}, a1v = {}, a2 = {}, a3 = {};
    #pragma unroll
    for (int ks = 0; ks < KS1; ++ks) {
      bf16x8 a = *(const bf16x8*)(A1p + lr * A1S + swz(lr, 64 * ks + 16 * q));
      b0 = __builtin_amdgcn_mfma_f32_16x16x32_bf16(a, w1[ks][0], b0, 0, 0, 0);
      b1 = __builtin_amdgcn_mfma_f32_16x16x32_bf16(a, w1[ks][1], b1, 0, 0, 0);
      b2 = __builtin_amdgcn_mfma_f32_16x16x32_bf16(a, w1[ks][2], b2, 0, 0, 0);
      b3 = __builtin_amdgcn_mfma_f32_16x16x32_bf16(a, w1[ks][3], b3, 0, 0, 0);
    }
    #pragma unroll
    for (int ks = 0; ks < KS0; ++ks) {
      bf16x8 a = *(const bf16x8*)(A0p + lr * A0S + swz(lr, 64 * ks + 16 * q));
      a0  = __builtin_amdgcn_mfma_f32_16x16x32_bf16(a, w0[ks][0], a0, 0, 0, 0);
      a1v = __builtin_amdgcn_mfma_f32_16x16x32_bf16(a, w0[ks][1], a1v, 0, 0, 0);
      a2  = __builtin_amdgcn_mfma_f32_16x16x32_bf16(a, w0[ks][2], a2, 0, 0, 0);
      a3  = __builtin_amdgcn_mfma_f32_16x16x32_bf16(a, w0[ks][3], a3, 0, 0, 0);
    }

    // stage x(i+2) -> A0[cur] (read next iter by L0(i+2))
    if (tid < 256 && xt == ((i + 2) & 7)) {
      u16x4 hi, lo;
      #pragma unroll
      for (int j = 0; j < 4; ++j) {
        hi[j] = f2bf(xa[j]);
        lo[j] = f2bf(xa[j] - bf2f(hi[j]));
      }
      char* buf = a0lds + cur * A0BUF;
      *(u16x4*)(buf + xs * A0S + swz(xs, 8 * xh))      = hi;
      *(u16x4*)(buf + xs * A0S + swz(xs, 16 + 8 * xh)) = lo;
    }

    char* A1n = a1lds + nxt * A1BUF;   // h0(i+1), h1(i+1) destination
    char* A0c = a0lds + cur * A0BUF;   // h0(i+1) destination for L0(i+2)

    // L1(i) update + output
    #pragma unroll
    for (int r = 0; r < 4; ++r) {
      const int row = 4 * q + r;
      float h = cell(b0[r] + bias1[0], b1[r] + bias1[1],
                     b2[r] + bias1[2], b3[r] + bias1[3], c1[r]);
      *(unsigned short*)(A1n + row * A1S + swz(row, 160 + 2 * n0)) = f2bf(h);
      if (i == len4[r] - 1) out[(size_t)seq4[r] * H_ + n0] = h;
    }
    // L0(i+1) update
    #pragma unroll
    for (int r = 0; r < 4; ++r) {
      const int row = 4 * q + r;
      float h = cell(a0[r] + bias0[0], a1v[r] + bias0[1],
                     a2[r] + bias0[2], a3[r] + bias0[3], c0[r]);
      unsigned short hb = f2bf(h);
      *(unsigned short*)(A1n + row * A1S + swz(row, 2 * n0)) = hb;
      *(unsigned short*)(A0c + row * A0S + swz(row, 32 + 2 * n0)) = hb;
    }
    __syncthreads();
  }
}

extern "C" void kernel_launch(void* const* d_in, const int* in_sizes, int n_in,
                              void* d_out, int out_size, void* d_ws, size_t ws_size,
                              hipStream_t stream) {
  const float* X    = (const float*)d_in[0];
  const float* Wih0 = (const float*)d_in[1];
  const float* Whh0 = (const float*)d_in[2];
  const float* bih0 = (const float*)d_in[3];
  const float* bhh0 = (const float*)d_in[4];
  const float* Wih1 = (const float*)d_in[5];
  const float* Whh1 = (const float*)d_in[6];
  const float* bih1 = (const float*)d_in[7];
  const float* bhh1 = (const float*)d_in[8];
  const int*   slen = (const int*)d_in[9];
  int* perm = (int*)d_ws;   // 2048 ints

  sort_by_len<<<1, 512, 0, stream>>>(slen, perm);
  lstm2_mfma<<<NBLK, NTH, 0, stream>>>(
      X, Wih0, Whh0, bih0, bhh0, Wih1, Whh1, bih1, bhh1, slen, perm,
      (float*)d_out);
}

// Round 6
// 770.858 us; speedup vs baseline: 4.3224x; 1.2925x over previous
//
#include <hip/hip_runtime.h>
#include <math.h>

#define B_   2048
#define T_   512
#define D_   8
#define H_   80
#define NB   16
#define NBLK (B_ / NB)     // 128 blocks
#define NTH  512           // 8 waves: (layer L, unit-block ub)
#define KS0  3             // A0: K=96  = [x_hi(8) | x_lo(8) | h0(80)]
#define KS1  5             // A1: K=160 = [h0(80) | h1(80)]
#define A0S  256           // A0 row stride bytes (128 bf16)
#define A1S  384           // A1 row stride bytes (192 bf16)
#define A0BUF (16 * A0S)   // 4 KB
#define A1BUF (16 * A1S)   // 6 KB

typedef float f32x4  __attribute__((ext_vector_type(4)));
typedef short bf16x8 __attribute__((ext_vector_type(8)));
typedef unsigned short u16x4 __attribute__((ext_vector_type(4)));

__device__ __forceinline__ float sigm(float x) {
  return __builtin_amdgcn_rcpf(1.0f + __expf(-x));
}
__device__ __forceinline__ unsigned short f2bf(float f) {  // RNE f32->bf16
  unsigned u = __builtin_bit_cast(unsigned, f);
  return (unsigned short)((u + 0x7FFFu + ((u >> 16) & 1u)) >> 16);
}
__device__ __forceinline__ float bf2f(unsigned short b) {
  unsigned u = ((unsigned)b) << 16;
  return __builtin_bit_cast(float, u);
}
__device__ __forceinline__ int swz(int row, int byte_in_row) {
  return byte_in_row ^ ((row & 7) << 4);
}
// full LSTM cell; tanh(x)=2*sigm(2x)-1 (overflow-safe)
__device__ __forceinline__ float cell(float gi, float gf, float gg, float go,
                                      float& c) {
  float si = sigm(gi), sf = sigm(gf);
  float tg = __builtin_fmaf(2.0f, sigm(2.0f * gg), -1.0f);
  c = sf * c + si * tg;
  float th = __builtin_fmaf(2.0f, sigm(2.0f * c), -1.0f);
  return sigm(go) * th;
}

// ---- counting sort by length, DESCENDING ----
__global__ __launch_bounds__(512)
void sort_by_len(const int* __restrict__ slen, int* __restrict__ perm) {
  __shared__ int cnt[513];
  const int tid = threadIdx.x;
  for (int i = tid; i < 513; i += 512) cnt[i] = 0;
  __syncthreads();
  for (int b = tid; b < B_; b += 512) atomicAdd(&cnt[T_ - slen[b]], 1);
  __syncthreads();
  if (tid == 0) { int s = 0;
    for (int k = 0; k < 513; ++k) { int c = cnt[k]; cnt[k] = s; s += c; } }
  __syncthreads();
  for (int b = tid; b < B_; b += 512) {
    int pos = atomicAdd(&cnt[T_ - slen[b]], 1);
    perm[pos] = b;   // equal-length order arbitrary: per-seq results independent
  }
}

// ---- fused 2-layer LSTM: 8 uniform waves = (layer, unit-block) roles ----
// wave w: L=w&1, ub=w>>1. Owns tiles (g=0..3, units 16ub..16ub+16) of layer L
// + tile (g=ub, units 64..79). Units 64..79 cells via gs4 LDS gate exchange.
// Skew: interval i computes L1(i) || L0(i+1). C layout: col=lane&15, row=4q+r.
__global__ __launch_bounds__(NTH, 2)
void lstm2_mfma(const float* __restrict__ X,
                const float* __restrict__ Wih0, const float* __restrict__ Whh0,
                const float* __restrict__ bih0, const float* __restrict__ bhh0,
                const float* __restrict__ Wih1, const float* __restrict__ Whh1,
                const float* __restrict__ bih1, const float* __restrict__ bhh1,
                const int* __restrict__ slen, const int* __restrict__ perm,
                float* __restrict__ out)
{
  __shared__ char a0lds[2 * A0BUF];
  __shared__ char a1lds[2 * A1BUF];
  __shared__ __align__(16) float gs4[2][NB][16][4];  // [L][seq][unit-64][gate]
  __shared__ int  pbs[NB];
  __shared__ int  lns[NB];

  const int tid = threadIdx.x;
  const int w   = tid >> 6;
  const int l   = tid & 63;
  const int lr  = l & 15;           // A-frag row / C col
  const int q   = l >> 4;           // k-octet / C row-block
  const int L   = w & 1;            // layer
  const int ub  = w >> 1;           // unit-block 0..3
  const int nU  = 16 * ub + lr;     // own unit (0..63)
  const int n4  = 80 * ub + 64 + lr;// u4-writer weight col (gate=ub, unit 64+lr)
  const int sequ = 4 * q + ub;      // u4-reader seq
  const int nu4  = 64 + lr;         // u4-reader unit

  if (tid < NB) {
    int pb = perm[blockIdx.x * NB + tid];
    pbs[tid] = pb;
    lns[tid] = slen[pb];
  }

  // ---- weight B-fragments. frag elem j <-> k = 32*ks + 8*q + j ----
  bf16x8 wf[5][KS1];
  float  bias[4], bias4;
  if (L == 0) {
    #pragma unroll
    for (int t = 0; t < 5; ++t) {
      const int n = (t < 4) ? (80 * t + nU) : n4;
      #pragma unroll
      for (int ks = 0; ks < KS0; ++ks) {
        bf16x8 v;
        #pragma unroll
        for (int j = 0; j < 8; ++j) {
          int k = 32 * ks + 8 * q + j;
          float f = (k < 8)  ? Wih0[n * D_ + k]
                  : (k < 16) ? Wih0[n * D_ + (k - 8)]
                             : Whh0[n * H_ + (k - 16)];
          v[j] = (short)f2bf(f);
        }
        wf[t][ks] = v;
      }
    }
    #pragma unroll
    for (int g = 0; g < 4; ++g) bias[g] = bih0[80 * g + nU] + bhh0[80 * g + nU];
    bias4 = bih0[n4] + bhh0[n4];
  } else {
    #pragma unroll
    for (int t = 0; t < 5; ++t) {
      const int n = (t < 4) ? (80 * t + nU) : n4;
      #pragma unroll
      for (int ks = 0; ks < KS1; ++ks) {
        bf16x8 v;
        #pragma unroll
        for (int j = 0; j < 8; ++j) {
          int k = 32 * ks + 8 * q + j;
          float f = (k < 80) ? Wih1[n * H_ + k] : Whh1[n * H_ + (k - 80)];
          v[j] = (short)f2bf(f);
        }
        wf[t][ks] = v;
      }
    }
    #pragma unroll
    for (int g = 0; g < 4; ++g) bias[g] = bih1[80 * g + nU] + bhh1[80 * g + nU];
    bias4 = bih1[n4] + bhh1[n4];
  }

  for (int i = tid; i < (2 * A0BUF) / 4; i += NTH) ((int*)a0lds)[i] = 0;
  for (int i = tid; i < (2 * A1BUF) / 4; i += NTH) ((int*)a1lds)[i] = 0;
  __syncthreads();                      // pbs/lns + zeros visible

  const int mlen = lns[0];
  int seq4[4], len4[4];
  #pragma unroll
  for (int r = 0; r < 4; ++r) { seq4[r] = pbs[4 * q + r]; len4[r] = lns[4 * q + r]; }
  const int pbU = pbs[sequ], lenU = lns[sequ];

  // ---- x machinery (waves 0-3): lane owns x[seq=xs][chunk+xt][4*xh..+4) ----
  const int xs = tid >> 4, xt = (tid & 15) >> 1, xh = tid & 1;
  const float* xbase = nullptr;
  f32x4 xa = {}, xb = {};
  if (tid < 256) {
    xbase = X + (size_t)pbs[xs] * (T_ * D_) + 4 * xh;
    int t0 = xt;     if (t0 > T_ - 1) t0 = T_ - 1;
    int t1 = 8 + xt; if (t1 > T_ - 1) t1 = T_ - 1;
    xa = *(const f32x4*)(xbase + t0 * D_);
    xb = *(const f32x4*)(xbase + t1 * D_);
  }
  #pragma unroll
  for (int tt = 0; tt < 2; ++tt) {
    if (tid < 256 && xt == tt) {
      u16x4 hi, lo;
      #pragma unroll
      for (int j = 0; j < 4; ++j) { hi[j] = f2bf(xa[j]); lo[j] = f2bf(xa[j] - bf2f(hi[j])); }
      char* buf = a0lds + tt * A0BUF;
      *(u16x4*)(buf + xs * A0S + swz(xs, 8 * xh))      = hi;
      *(u16x4*)(buf + xs * A0S + swz(xs, 16 + 8 * xh)) = lo;
    }
  }
  __syncthreads();                      // x(0), x(1) visible

  float c[4] = {0.f, 0.f, 0.f, 0.f};    // own-cell state (layer L)
  float cu4  = 0.f;                     // u4-cell state (layer L)

  // ---- prologue: L0(0) on L0 waves ----
  {
    f32x4 acc[5] = {};
    if (L == 0) {
      #pragma unroll
      for (int ks = 0; ks < KS0; ++ks) {
        bf16x8 a = *(const bf16x8*)(a0lds + lr * A0S + swz(lr, 64 * ks + 16 * q));
        #pragma unroll
        for (int t = 0; t < 5; ++t)
          acc[t] = __builtin_amdgcn_mfma_f32_16x16x32_bf16(a, wf[t][ks], acc[t], 0, 0, 0);
      }
      #pragma unroll
      for (int r = 0; r < 4; ++r) gs4[0][4 * q + r][lr][ub] = acc[4][r] + bias4;
    }
    __syncthreads();
    if (L == 0) {
      char* A1w = a1lds;                // A1[0] h0-region
      char* A0w = a0lds + A0BUF;        // A0[1]
      #pragma unroll
      for (int r = 0; r < 4; ++r) {
        const int row = 4 * q + r;
        float h = cell(acc[0][r] + bias[0], acc[1][r] + bias[1],
                       acc[2][r] + bias[2], acc[3][r] + bias[3], c[r]);
        unsigned short hb = f2bf(h);
        *(unsigned short*)(A1w + row * A1S + swz(row, 2 * nU)) = hb;
        *(unsigned short*)(A0w + row * A0S + swz(row, 32 + 2 * nU)) = hb;
      }
      f32x4 y = *(const f32x4*)&gs4[0][sequ][lr][0];
      float h4 = cell(y[0], y[1], y[2], y[3], cu4);
      unsigned short hb4 = f2bf(h4);
      *(unsigned short*)(A1w + sequ * A1S + swz(sequ, 2 * nu4)) = hb4;
      *(unsigned short*)(A0w + sequ * A0S + swz(sequ, 32 + 2 * nu4)) = hb4;
    }
    __syncthreads();
  }

  // ---- main loop: interval i = { L1(i) on L1-waves || L0(i+1) on L0-waves } ----
  #pragma unroll 1
  for (int i = 0; i < mlen; ++i) {
    const int cur = i & 1, nxt = cur ^ 1;

    if (tid < 256 && ((i + 2) & 7) == 0) {          // rotate x chunk regs
      xa = xb;
      int tc = i + 10 + xt; if (tc > T_ - 1) tc = T_ - 1;
      xb = *(const f32x4*)(xbase + tc * D_);
    }

    f32x4 acc[5] = {};
    if (L == 1) {
      const char* A1p = a1lds + cur * A1BUF;
      #pragma unroll
      for (int ks = 0; ks < KS1; ++ks) {
        bf16x8 a = *(const bf16x8*)(A1p + lr * A1S + swz(lr, 64 * ks + 16 * q));
        #pragma unroll
        for (int t = 0; t < 5; ++t)
          acc[t] = __builtin_amdgcn_mfma_f32_16x16x32_bf16(a, wf[t][ks], acc[t], 0, 0, 0);
      }
      #pragma unroll
      for (int r = 0; r < 4; ++r) gs4[1][4 * q + r][lr][ub] = acc[4][r] + bias4;
    } else {
      const char* A0p = a0lds + nxt * A0BUF;
      #pragma unroll
      for (int ks = 0; ks < KS0; ++ks) {
        bf16x8 a = *(const bf16x8*)(A0p + lr * A0S + swz(lr, 64 * ks + 16 * q));
        #pragma unroll
        for (int t = 0; t < 5; ++t)
          acc[t] = __builtin_amdgcn_mfma_f32_16x16x32_bf16(a, wf[t][ks], acc[t], 0, 0, 0);
      }
      #pragma unroll
      for (int r = 0; r < 4; ++r) gs4[0][4 * q + r][lr][ub] = acc[4][r] + bias4;
    }

    if (tid < 256 && xt == ((i + 2) & 7)) {          // stage x(i+2) -> A0[cur]
      u16x4 hi, lo;
      #pragma unroll
      for (int j = 0; j < 4; ++j) { hi[j] = f2bf(xa[j]); lo[j] = f2bf(xa[j] - bf2f(hi[j])); }
      char* buf = a0lds + cur * A0BUF;
      *(u16x4*)(buf + xs * A0S + swz(xs, 8 * xh))      = hi;
      *(u16x4*)(buf + xs * A0S + swz(xs, 16 + 8 * xh)) = lo;
    }
    __syncthreads();    // barrier A: gs4 visible

    char* A1n = a1lds + nxt * A1BUF;
    char* A0c = a0lds + cur * A0BUF;

    if (L == 1) {
      #pragma unroll
      for (int r = 0; r < 4; ++r) {
        const int row = 4 * q + r;
        float h = cell(acc[0][r] + bias[0], acc[1][r] + bias[1],
                       acc[2][r] + bias[2], acc[3][r] + bias[3], c[r]);
        *(unsigned short*)(A1n + row * A1S + swz(row, 160 + 2 * nU)) = f2bf(h);
        if (i == len4[r] - 1) out[(size_t)seq4[r] * H_ + nU] = h;
      }
      f32x4 y = *(const f32x4*)&gs4[1][sequ][lr][0];
      float h4 = cell(y[0], y[1], y[2], y[3], cu4);
      *(unsigned short*)(A1n + sequ * A1S + swz(sequ, 160 + 2 * nu4)) = f2bf(h4);
      if (i == lenU - 1) out[(size_t)pbU * H_ + nu4] = h4;
    } else {
      #pragma unroll
      for (int r = 0; r < 4; ++r) {
        const int row = 4 * q + r;
        float h = cell(acc[0][r] + bias[0], acc[1][r] + bias[1],
                       acc[2][r] + bias[2], acc[3][r] + bias[3], c[r]);
        unsigned short hb = f2bf(h);
        *(unsigned short*)(A1n + row * A1S + swz(row, 2 * nU)) = hb;
        *(unsigned short*)(A0c + row * A0S + swz(row, 32 + 2 * nU)) = hb;
      }
      f32x4 y = *(const f32x4*)&gs4[0][sequ][lr][0];
      float h4 = cell(y[0], y[1], y[2], y[3], cu4);
      unsigned short hb4 = f2bf(h4);
      *(unsigned short*)(A1n + sequ * A1S + swz(sequ, 2 * nu4)) = hb4;
      *(unsigned short*)(A0c + sequ * A0S + swz(sequ, 32 + 2 * nu4)) = hb4;
    }
    __syncthreads();    // barrier B
  }
}

extern "C" void kernel_launch(void* const* d_in, const int* in_sizes, int n_in,
                              void* d_out, int out_size, void* d_ws, size_t ws_size,
                              hipStream_t stream) {
  const float* X    = (const float*)d_in[0];
  const float* Wih0 = (const float*)d_in[1];
  const float* Whh0 = (const float*)d_in[2];
  const float* bih0 = (const float*)d_in[3];
  const float* bhh0 = (const float*)d_in[4];
  const float* Wih1 = (const float*)d_in[5];
  const float* Whh1 = (const float*)d_in[6];
  const float* bih1 = (const float*)d_in[7];
  const float* bhh1 = (const float*)d_in[8];
  const int*   slen = (const int*)d_in[9];
  int* perm = (int*)d_ws;   // 2048 ints

  sort_by_len<<<1, 512, 0, stream>>>(slen, perm);
  lstm2_mfma<<<NBLK, NTH, 0, stream>>>(
      X, Wih0, Whh0, bih0, bhh0, Wih1, Whh1, bih1, bhh1, slen, perm,
      (float*)d_out);
}

// Round 7
// 735.033 us; speedup vs baseline: 4.5331x; 1.0487x over previous
//
#include <hip/hip_runtime.h>
#include <math.h>

#define B_   2048
#define T_   512
#define D_   8
#define H_   80
#define NB   16
#define NBLK (B_ / NB)     // 128 blocks
#define NTH  640           // 10 waves: (layer L in {0,1}) x (unit-block v in 0..4)
#define KS0  3             // A0: K=96  = [x_hi(8) | x_lo(8) | h0(80)]
#define KS1  5             // A1: K=160 = [h0(80) | h1(80)]
#define A0S  256           // A0 row stride bytes (128 bf16)
#define A1S  384           // A1 row stride bytes (192 bf16)
#define A0BUF (16 * A0S)   // 4 KB
#define A1BUF (16 * A1S)   // 6 KB

typedef float f32x4  __attribute__((ext_vector_type(4)));
typedef short bf16x8 __attribute__((ext_vector_type(8)));
typedef unsigned short u16x4 __attribute__((ext_vector_type(4)));

__device__ __forceinline__ float sigm(float x) {
  return __builtin_amdgcn_rcpf(1.0f + __expf(-x));
}
__device__ __forceinline__ unsigned short f2bf(float f) {  // RNE f32->bf16
  unsigned u = __builtin_bit_cast(unsigned, f);
  return (unsigned short)((u + 0x7FFFu + ((u >> 16) & 1u)) >> 16);
}
__device__ __forceinline__ float bf2f(unsigned short b) {
  unsigned u = ((unsigned)b) << 16;
  return __builtin_bit_cast(float, u);
}
__device__ __forceinline__ int swz(int row, int byte_in_row) {
  return byte_in_row ^ ((row & 7) << 4);
}
// full LSTM cell; tanh(x)=2*sigm(2x)-1 (overflow-safe)
__device__ __forceinline__ float cell(float gi, float gf, float gg, float go,
                                      float& c) {
  float si = sigm(gi), sf = sigm(gf);
  float tg = __builtin_fmaf(2.0f, sigm(2.0f * gg), -1.0f);
  c = sf * c + si * tg;
  float th = __builtin_fmaf(2.0f, sigm(2.0f * c), -1.0f);
  return sigm(go) * th;
}

// ---- counting sort by length, DESCENDING ----
__global__ __launch_bounds__(512)
void sort_by_len(const int* __restrict__ slen, int* __restrict__ perm) {
  __shared__ int cnt[513];
  const int tid = threadIdx.x;
  for (int i = tid; i < 513; i += 512) cnt[i] = 0;
  __syncthreads();
  for (int b = tid; b < B_; b += 512) atomicAdd(&cnt[T_ - slen[b]], 1);
  __syncthreads();
  if (tid == 0) { int s = 0;
    for (int k = 0; k < 513; ++k) { int c = cnt[k]; cnt[k] = s; s += c; } }
  __syncthreads();
  for (int b = tid; b < B_; b += 512) {
    int pos = atomicAdd(&cnt[T_ - slen[b]], 1);
    perm[pos] = b;   // equal-length order arbitrary: per-seq results independent
  }
}

// ---- fused 2-layer LSTM: 10 waves, wave = (layer, 16-unit block) ----
// Wave (L, v) owns ALL FOUR gate tiles of units [16v, 16v+16) of layer L ->
// cell update is fully lane-local (acc[g][r] = gate g, seq 4q+r, unit 16v+lr).
// NO gate exchange; ONE barrier per interval. Skew: interval i = L1(i)||L0(i+1).
__global__ __launch_bounds__(NTH)
void lstm2_mfma(const float* __restrict__ X,
                const float* __restrict__ Wih0, const float* __restrict__ Whh0,
                const float* __restrict__ bih0, const float* __restrict__ bhh0,
                const float* __restrict__ Wih1, const float* __restrict__ Whh1,
                const float* __restrict__ bih1, const float* __restrict__ bhh1,
                const int* __restrict__ slen, const int* __restrict__ perm,
                float* __restrict__ out)
{
  __shared__ char a0lds[2 * A0BUF];
  __shared__ char a1lds[2 * A1BUF];
  __shared__ int  pbs[NB];
  __shared__ int  lns[NB];

  const int tid = threadIdx.x;
  const int w   = tid >> 6;
  const int l   = tid & 63;
  const int lr  = l & 15;           // A-frag row / C col
  const int q   = l >> 4;           // k-octet / C row-block
  const int L   = (w < 5) ? 0 : 1;  // layer
  const int v   = w - 5 * L;        // unit-block 0..4
  const int u   = 16 * v + lr;      // own unit (0..79)

  if (tid < NB) {
    int pb = perm[blockIdx.x * NB + tid];
    pbs[tid] = pb;
    lns[tid] = slen[pb];
  }

  // ---- weight B-fragments: tile g covers gate g, units 16v..16v+15 ----
  // frag elem j <-> k = 32*ks + 8*q + j, col lr <-> unit 16v+lr.
  bf16x8 wf[4][KS1];
  float  bias[4];
  if (L == 0) {
    #pragma unroll
    for (int g = 0; g < 4; ++g) {
      const int n = 80 * g + u;
      bias[g] = bih0[n] + bhh0[n];
      #pragma unroll
      for (int ks = 0; ks < KS0; ++ks) {
        bf16x8 vv;
        #pragma unroll
        for (int j = 0; j < 8; ++j) {
          int k = 32 * ks + 8 * q + j;
          float f = (k < 8)  ? Wih0[n * D_ + k]
                  : (k < 16) ? Wih0[n * D_ + (k - 8)]
                             : Whh0[n * H_ + (k - 16)];
          vv[j] = (short)f2bf(f);
        }
        wf[g][ks] = vv;
      }
    }
  } else {
    #pragma unroll
    for (int g = 0; g < 4; ++g) {
      const int n = 80 * g + u;
      bias[g] = bih1[n] + bhh1[n];
      #pragma unroll
      for (int ks = 0; ks < KS1; ++ks) {
        bf16x8 vv;
        #pragma unroll
        for (int j = 0; j < 8; ++j) {
          int k = 32 * ks + 8 * q + j;
          float f = (k < 80) ? Wih1[n * H_ + k] : Whh1[n * H_ + (k - 80)];
          vv[j] = (short)f2bf(f);
        }
        wf[g][ks] = vv;
      }
    }
  }

  for (int i = tid; i < (2 * A0BUF) / 4; i += NTH) ((int*)a0lds)[i] = 0;
  for (int i = tid; i < (2 * A1BUF) / 4; i += NTH) ((int*)a1lds)[i] = 0;
  __syncthreads();                      // pbs/lns + zeros visible

  const int mlen = lns[0];
  int seq4[4], len4[4];
  #pragma unroll
  for (int r = 0; r < 4; ++r) { seq4[r] = pbs[4 * q + r]; len4[r] = lns[4 * q + r]; }

  // ---- x machinery (waves 0-3, all L0): lane owns x[xs][chunk+xt][4xh..+4) ----
  const int xs = tid >> 4, xt = (tid & 15) >> 1, xh = tid & 1;
  const float* xbase = nullptr;
  f32x4 xa = {}, xb = {};
  if (tid < 256) {
    xbase = X + (size_t)pbs[xs] * (T_ * D_) + 4 * xh;
    int t0 = xt;     if (t0 > T_ - 1) t0 = T_ - 1;
    int t1 = 8 + xt; if (t1 > T_ - 1) t1 = T_ - 1;
    xa = *(const f32x4*)(xbase + t0 * D_);
    xb = *(const f32x4*)(xbase + t1 * D_);
  }
  #pragma unroll
  for (int tt = 0; tt < 2; ++tt) {
    if (tid < 256 && xt == tt) {
      u16x4 hi, lo;
      #pragma unroll
      for (int j = 0; j < 4; ++j) { hi[j] = f2bf(xa[j]); lo[j] = f2bf(xa[j] - bf2f(hi[j])); }
      char* buf = a0lds + tt * A0BUF;
      *(u16x4*)(buf + xs * A0S + swz(xs, 8 * xh))      = hi;
      *(u16x4*)(buf + xs * A0S + swz(xs, 16 + 8 * xh)) = lo;
    }
  }
  __syncthreads();                      // x(0), x(1) visible

  float c[4] = {0.f, 0.f, 0.f, 0.f};

  // ---- prologue: L0(0) on L0 waves ----
  if (L == 0) {
    f32x4 acc[4] = {};
    #pragma unroll
    for (int ks = 0; ks < KS0; ++ks) {
      bf16x8 a = *(const bf16x8*)(a0lds + lr * A0S + swz(lr, 64 * ks + 16 * q));
      #pragma unroll
      for (int g = 0; g < 4; ++g)
        acc[g] = __builtin_amdgcn_mfma_f32_16x16x32_bf16(a, wf[g][ks], acc[g], 0, 0, 0);
    }
    char* A1w = a1lds;                  // A1[0] h0-region
    char* A0w = a0lds + A0BUF;          // A0[1] h0-region
    #pragma unroll
    for (int r = 0; r < 4; ++r) {
      const int row = 4 * q + r;
      float h = cell(acc[0][r] + bias[0], acc[1][r] + bias[1],
                     acc[2][r] + bias[2], acc[3][r] + bias[3], c[r]);
      unsigned short hb = f2bf(h);
      *(unsigned short*)(A1w + row * A1S + swz(row, 2 * u)) = hb;
      *(unsigned short*)(A0w + row * A0S + swz(row, 32 + 2 * u)) = hb;
    }
  }
  __syncthreads();                      // h0(0), x(1) visible

  // ---- main loop: interval i = { L1(i) || L0(i+1) }, ONE barrier ----
  #pragma unroll 2
  for (int i = 0; i < mlen; ++i) {
    const int cur = i & 1, nxt = cur ^ 1;

    if (tid < 256 && ((i + 2) & 7) == 0) {          // rotate x chunk regs
      xa = xb;
      int tc = i + 10 + xt; if (tc > T_ - 1) tc = T_ - 1;
      xb = *(const f32x4*)(xbase + tc * D_);
    }

    f32x4 acc[4] = {};
    if (L == 1) {
      const char* A1p = a1lds + cur * A1BUF;        // L1(i) input [h0(i)|h1(i-1)]
      #pragma unroll
      for (int ks = 0; ks < KS1; ++ks) {
        bf16x8 a = *(const bf16x8*)(A1p + lr * A1S + swz(lr, 64 * ks + 16 * q));
        #pragma unroll
        for (int g = 0; g < 4; ++g)
          acc[g] = __builtin_amdgcn_mfma_f32_16x16x32_bf16(a, wf[g][ks], acc[g], 0, 0, 0);
      }
    } else {
      const char* A0p = a0lds + nxt * A0BUF;        // L0(i+1) input [x(i+1)|h0(i)]
      #pragma unroll
      for (int ks = 0; ks < KS0; ++ks) {
        bf16x8 a = *(const bf16x8*)(A0p + lr * A0S + swz(lr, 64 * ks + 16 * q));
        #pragma unroll
        for (int g = 0; g < 4; ++g)
          acc[g] = __builtin_amdgcn_mfma_f32_16x16x32_bf16(a, wf[g][ks], acc[g], 0, 0, 0);
      }
    }

    if (tid < 256 && xt == ((i + 2) & 7)) {          // stage x(i+2) -> A0[cur]
      u16x4 hi, lo;
      #pragma unroll
      for (int j = 0; j < 4; ++j) { hi[j] = f2bf(xa[j]); lo[j] = f2bf(xa[j] - bf2f(hi[j])); }
      char* buf = a0lds + cur * A0BUF;
      *(u16x4*)(buf + xs * A0S + swz(xs, 8 * xh))      = hi;
      *(u16x4*)(buf + xs * A0S + swz(xs, 16 + 8 * xh)) = lo;
    }

    char* A1n = a1lds + nxt * A1BUF;
    char* A0c = a0lds + cur * A0BUF;

    if (L == 1) {                        // L1(i) cells + output
      #pragma unroll
      for (int r = 0; r < 4; ++r) {
        const int row = 4 * q + r;
        float h = cell(acc[0][r] + bias[0], acc[1][r] + bias[1],
                       acc[2][r] + bias[2], acc[3][r] + bias[3], c[r]);
        *(unsigned short*)(A1n + row * A1S + swz(row, 160 + 2 * u)) = f2bf(h);
        if (i == len4[r] - 1) out[(size_t)seq4[r] * H_ + u] = h;
      }
    } else {                             // L0(i+1) cells
      #pragma unroll
      for (int r = 0; r < 4; ++r) {
        const int row = 4 * q + r;
        float h = cell(acc[0][r] + bias[0], acc[1][r] + bias[1],
                       acc[2][r] + bias[2], acc[3][r] + bias[3], c[r]);
        unsigned short hb = f2bf(h);
        *(unsigned short*)(A1n + row * A1S + swz(row, 2 * u)) = hb;
        *(unsigned short*)(A0c + row * A0S + swz(row, 32 + 2 * u)) = hb;
      }
    }
    __syncthreads();
  }
}

extern "C" void kernel_launch(void* const* d_in, const int* in_sizes, int n_in,
                              void* d_out, int out_size, void* d_ws, size_t ws_size,
                              hipStream_t stream) {
  const float* X    = (const float*)d_in[0];
  const float* Wih0 = (const float*)d_in[1];
  const float* Whh0 = (const float*)d_in[2];
  const float* bih0 = (const float*)d_in[3];
  const float* bhh0 = (const float*)d_in[4];
  const float* Wih1 = (const float*)d_in[5];
  const float* Whh1 = (const float*)d_in[6];
  const float* bih1 = (const float*)d_in[7];
  const float* bhh1 = (const float*)d_in[8];
  const int*   slen = (const int*)d_in[9];
  int* perm = (int*)d_ws;   // 2048 ints

  sort_by_len<<<1, 512, 0, stream>>>(slen, perm);
  lstm2_mfma<<<NBLK, NTH, 0, stream>>>(
      X, Wih0, Whh0, bih0, bhh0, Wih1, Whh1, bih1, bhh1, slen, perm,
      (float*)d_out);
}